// Round 11
// baseline (208.705 us; speedup 1.0000x reference)
//
#include <hip/hip_runtime.h>
#include <math.h>

#define NN 10000
#define EE 320000
#define PP 200000
#define NTILES 320   // 10240/32 global 32-K tiles for W frag packing

typedef _Float16 h8v __attribute__((ext_vector_type(8)));  // 8 fp16 (A/B frag)
typedef __attribute__((ext_vector_type(4))) float f4v;     // 4 f32  (C/D frag)

#define GLOAD_LDS16(gsrc, ldst)                                                        \
    __builtin_amdgcn_global_load_lds((const __attribute__((address_space(1))) void*)(gsrc), \
                                     (__attribute__((address_space(3))) void*)(ldst), 16, 0, 0)

// fp32 -> fp16 RTNE bit pattern
__device__ __forceinline__ ushort f2h(float f) {
    union { _Float16 h; ushort u; } c;
    c.h = (_Float16)f;
    return c.u;
}

// ---------------- degree / norm ----------------
__global__ void k_deg_count(const int* __restrict__ dst, int* __restrict__ degi) {
    int e = blockIdx.x * blockDim.x + threadIdx.x;
    if (e < EE) atomicAdd(&degi[dst[e]], 1);
}

__global__ void k_dinv(const int* __restrict__ degi, float* __restrict__ dinv) {
    int n = blockIdx.x * blockDim.x + threadIdx.x;
    if (n < NN) dinv[n] = rsqrtf((float)(degi[n] + 1));  // +1 self loop
}

// ---------------- W1 -> fp16 in MFMA-fragment order ----------------
// w1f[((g*2+ct)*64 + lane)*8 + e] = fp16(W1[k][col]), k=g*32+(lane>>4)*8+e,
// col=ct*16+(lane&15); zero for k>=NN. 320*2*64*8 = 327,680 ushorts = 163,840 floats.
__global__ void k_wprep(const float* __restrict__ W1, ushort* __restrict__ wf) {
    int t = blockIdx.x * blockDim.x + threadIdx.x;
    if (t >= NTILES * 2 * 64 * 8) return;
    int e = t & 7, lane = (t >> 3) & 63, ct = (t >> 9) & 1, g = t >> 10;
    int col = ct * 16 + (lane & 15);
    int k = g * 32 + (lane >> 4) * 8 + e;
    wf[t] = (k < NN) ? f2h(W1[(long)k * 32 + col]) : (ushort)0;
}

// ---------------- GEMM1: h1_pre = x @ W1 (10000x10000 @ 10000x32), fp16 MFMA ----------------
// HBM-granule-optimized staging (512 B contiguous per row per inst, sequential row
// streams); fp16 fragments. Block = 64 rows x 640-K split; waves own 16 rows; W chunk
// (40 KB frag-packed fp16) staged ONCE per block. Per-wave 3-buffer x ring (pair
// stride 260 floats), unrolled 5-tile loop, literal counted vmcnt waits, lgkmcnt
// fencing before buffer overwrite. NO atomics: plain stores to per-split partials
// (h1_part strictly AFTER w1f in ws -- the R8/R9 aliasing bug is fixed).
// Grid (157,16); 1 block/CU (141 KB LDS).
__global__ __launch_bounds__(256) void k_gemm1(const float* __restrict__ x,
                                               const ushort* __restrict__ w1f,
                                               const float* __restrict__ zp,
                                               float* __restrict__ h1_part) {
    __shared__ __align__(16) float  xs[4 * 3 * 2080];    // 99,840 B: [wave][buf][8 pairs x 260]
    __shared__ __align__(16) ushort wlds[2560 * 8];      // 40,960 B: [g][ct][lane][8]
    const int tid = threadIdx.x;
    const int lane = tid & 63;
    const int w = tid >> 6;            // wave 0..3
    const int fl = lane & 15;          // fragment row/col within 16
    const int khi = lane >> 4;         // fragment k-group 0..3
    const int ks = blockIdx.y;         // K-split 0..15
    const int wrow0 = blockIdx.x * 64 + w * 16;   // this wave's first row
    const int k_begin = ks * 640;
    const long NN2 = (long)NN * NN;

    f4v acc0 = (f4v){0.f, 0.f, 0.f, 0.f};
    f4v acc1 = (f4v){0.f, 0.f, 0.f, 0.f};

    // ---- stage W chunk for this K-split (once, 10 gload_lds per thread-wave) ----
#pragma unroll
    for (int i = 0; i < 10; ++i) {
        const int ul = i * 256 + w * 64 + lane;           // unit id (g,ct,lane)
        const ushort* srcw =
            w1f + (((long)(ks * 20 + (ul >> 7)) * 2 + ((ul >> 6) & 1)) * 64 + lane) * 8;
        GLOAD_LDS16(srcw, &wlds[(long)(i * 256 + w * 64) * 8]);
    }
    __syncthreads();   // one-time drain: W visible to all waves; x not yet issued

    // ---- x staging: tile t = 128 K-floats; 8 insts, each 2 rows x 512 B contiguous ----
    const int sub = lane >> 5;          // which row of the pair
    const int kof = (lane & 31) * 4;    // float offset within row chunk
    auto stage = [&](int buf, int t) {
        const int k0 = k_begin + t * 128;
        float* dst = &xs[(w * 3 + buf) * 2080];
#pragma unroll
        for (int p = 0; p < 8; ++p) {
            long flat = (long)(wrow0 + p * 2 + sub) * NN + k0 + kof;
            const float* src = (flat + 4 <= NN2) ? (x + flat) : zp;  // OOB rows/tail -> 0
            GLOAD_LDS16(src, dst + p * 260);
        }
    };
    auto compute = [&](int buf, int t) {
        const float4* xrow =
            (const float4*)&xs[(w * 3 + buf) * 2080 + (fl >> 1) * 260 + (fl & 1) * 128];
#pragma unroll
        for (int kk = 0; kk < 4; ++kk) {
            const int gl = t * 4 + kk;
            h8v b0 = *(const h8v*)&wlds[((gl * 2 + 0) * 64 + lane) * 8];
            h8v b1 = *(const h8v*)&wlds[((gl * 2 + 1) * 64 + lane) * 8];
            float4 f0 = xrow[kk * 8 + khi * 2];
            float4 f1 = xrow[kk * 8 + khi * 2 + 1];
            union { h8v v; _Float16 h[8]; } a;
            a.h[0] = (_Float16)f0.x; a.h[1] = (_Float16)f0.y;
            a.h[2] = (_Float16)f0.z; a.h[3] = (_Float16)f0.w;
            a.h[4] = (_Float16)f1.x; a.h[5] = (_Float16)f1.y;
            a.h[6] = (_Float16)f1.z; a.h[7] = (_Float16)f1.w;
            acc0 = __builtin_amdgcn_mfma_f32_16x16x32_f16(a.v, b0, acc0, 0, 0, 0);
            acc1 = __builtin_amdgcn_mfma_f32_16x16x32_f16(a.v, b1, acc1, 0, 0, 0);
        }
    };

#define WAITV(n) asm volatile("s_waitcnt vmcnt(" #n ")" ::: "memory"); __builtin_amdgcn_sched_barrier(0)
#define WAITL()  asm volatile("s_waitcnt lgkmcnt(0)" ::: "memory");    __builtin_amdgcn_sched_barrier(0)

    stage(0, 0); stage(1, 1); stage(2, 2);               // 24 loads in flight
    WAITV(16); compute(0, 0); WAITL(); stage(0, 3);      // t=0
    WAITV(16); compute(1, 1); WAITL(); stage(1, 4);      // t=1
    WAITV(16); compute(2, 2);                            // t=2
    WAITV(8);  compute(0, 3);                            // t=3
    WAITV(0);  compute(1, 4);                            // t=4
#undef WAITV
#undef WAITL

    // ---- epilogue: plain stores to per-split partials (no atomics) ----
    const long pbase = (long)ks * NN * 32;
#pragma unroll
    for (int ct = 0; ct < 2; ++ct) {
        f4v a = ct ? acc1 : acc0;
        const int col = ct * 16 + fl;
#pragma unroll
        for (int r = 0; r < 4; ++r) {
            int g = wrow0 + khi * 4 + r;                 // C/D row = khi*4 + reg (m89)
            if (g < NN) h1_part[pbase + (long)g * 32 + col] = a[r];
        }
    }
}

// ---------------- reduce partials + self-loop init (fused) ----------------
__global__ void k_selfinit1(const float* __restrict__ h1_part, const float* __restrict__ dinv,
                            float* __restrict__ h1_pre, float* __restrict__ out1) {
    int t = blockIdx.x * blockDim.x + threadIdx.x;
    if (t < NN * 32) {
        float sum = 0.f;
#pragma unroll
        for (int ks = 0; ks < 16; ++ks) sum += h1_part[(long)ks * NN * 32 + t];
        int n = t >> 5;
        float di = dinv[n];
        h1_pre[t] = sum;
        out1[t] = di * di * sum;
    }
}

__global__ void k_scatter1(const int* __restrict__ src, const int* __restrict__ dst,
                           const float* __restrict__ dinv, const float* __restrict__ h1_pre,
                           float* __restrict__ out1) {
    int t = blockIdx.x * blockDim.x + threadIdx.x;
    if (t >= EE * 32) return;
    int e = t >> 5, c = t & 31;
    int s = src[e], d = dst[e];
    float nrm = dinv[s] * dinv[d];
    atomicAdd(&out1[d * 32 + c], h1_pre[s * 32 + c] * nrm);
}

__global__ void k_bias_relu1(float* __restrict__ out1, const float* __restrict__ b1) {
    int t = blockIdx.x * blockDim.x + threadIdx.x;
    if (t < NN * 32) out1[t] = fmaxf(out1[t] + b1[t & 31], 0.f);
}

// ---------------- GEMM2: h2_pre = out1 @ W2  (10000x32 @ 32x16), fp32 ----------------
__global__ __launch_bounds__(256) void k_gemm2(const float* __restrict__ out1,
                                               const float* __restrict__ W2,
                                               float* __restrict__ h2_pre) {
    __shared__ float w2s[512];
    int tid = threadIdx.x;
    w2s[tid] = W2[tid & 511];
    if (tid < 256) w2s[256 + tid] = W2[256 + tid];
    __syncthreads();
    int c = tid & 15, yloc = tid >> 4;
    int n = blockIdx.x * 16 + yloc;
    if (n < NN) {
        float a = 0.f;
#pragma unroll
        for (int k = 0; k < 32; ++k) a += out1[n * 32 + k] * w2s[k * 16 + c];
        h2_pre[n * 16 + c] = a;
    }
}

// ---------------- aggregation layer 2 (16 feats) ----------------
__global__ void k_selfinit2(const float* __restrict__ h2_pre, const float* __restrict__ dinv,
                            float* __restrict__ out2) {
    int t = blockIdx.x * blockDim.x + threadIdx.x;
    if (t < NN * 16) {
        int n = t >> 4;
        float di = dinv[n];
        out2[t] = di * di * h2_pre[t];
    }
}

__global__ void k_scatter2(const int* __restrict__ src, const int* __restrict__ dst,
                           const float* __restrict__ dinv, const float* __restrict__ h2_pre,
                           float* __restrict__ out2) {
    int t = blockIdx.x * blockDim.x + threadIdx.x;
    if (t >= EE * 16) return;
    int e = t >> 4, c = t & 15;
    int s = src[e], d = dst[e];
    float nrm = dinv[s] * dinv[d];
    atomicAdd(&out2[d * 16 + c], h2_pre[s * 16 + c] * nrm);
}

// ---------------- final: per-node partial dots with Wfc ----------------
__global__ void k_final2(const float* __restrict__ out2, const float* __restrict__ b2,
                         const float* __restrict__ Wfc, float* __restrict__ s_arr,
                         float* __restrict__ t_arr) {
    int n = blockIdx.x * blockDim.x + threadIdx.x;
    if (n >= NN) return;
    float s = 0.f, t = 0.f;
#pragma unroll
    for (int c = 0; c < 16; ++c) {
        float v = out2[n * 16 + c] + b2[c];
        s += v * Wfc[c];
        t += v * Wfc[16 + c];
    }
    s_arr[n] = s;
    t_arr[n] = t;
}

// ---------------- pair scoring ----------------
__global__ void k_pairs(const int* __restrict__ pair, const float* __restrict__ s_arr,
                        const float* __restrict__ t_arr, const float* __restrict__ bfc,
                        float* __restrict__ out) {
    int p = blockIdx.x * blockDim.x + threadIdx.x;
    if (p >= PP) return;
    const int2 ab = ((const int2*)pair)[p];
    float z = s_arr[ab.x] + t_arr[ab.y] + bfc[0];
    out[p] = 1.f / (1.f + expf(-z));
}

extern "C" void kernel_launch(void* const* d_in, const int* in_sizes, int n_in,
                              void* d_out, int out_size, void* d_ws, size_t ws_size,
                              hipStream_t stream) {
    const float* x    = (const float*)d_in[0];
    const int*   edge = (const int*)d_in[1];   // [2][E]
    const int*   pair = (const int*)d_in[2];   // [P][2]
    const float* W1   = (const float*)d_in[3];
    const float* b1   = (const float*)d_in[4];
    const float* W2   = (const float*)d_in[5];
    const float* b2   = (const float*)d_in[6];
    const float* Wfc  = (const float*)d_in[7];
    const float* bfc  = (const float*)d_in[8];
    float* out = (float*)d_out;
    float* ws  = (float*)d_ws;

    const int* src = edge;
    const int* dst = edge + EE;

    // workspace layout (floats)
    int*    degi    = (int*)ws;            // N
    float*  dinv    = ws + NN;             // N
    float*  h1_pre  = ws + 2 * NN;         // 32N
    float*  out1    = ws + 34 * NN;        // 32N
    float*  h2_pre  = ws + 66 * NN;        // 16N
    float*  out2    = ws + 82 * NN;        // 16N
    float*  s_arr   = ws + 98 * NN;        // N
    float*  t_arr   = ws + 99 * NN;        // N
    float*  zp      = ws + 100 * NN;       // 256 floats zero page
    ushort* w1f     = (ushort*)(ws + 100 * NN + 256);   // 327,680 ushorts = 163,840 floats
    float*  h1_part = ws + 100 * NN + 256 + 163840;     // AFTER w1f (R8/R9 bug: was +81920)

    hipMemsetAsync(degi, 0, NN * sizeof(int), stream);
    hipMemsetAsync(zp, 0, 1024, stream);

    k_deg_count<<<(EE + 255) / 256, 256, 0, stream>>>(dst, degi);
    k_dinv<<<(NN + 255) / 256, 256, 0, stream>>>(degi, dinv);
    k_wprep<<<(NTILES * 2 * 64 * 8 + 255) / 256, 256, 0, stream>>>(W1, w1f);

    k_gemm1<<<dim3(157, 16), 256, 0, stream>>>(x, w1f, zp, h1_part);

    k_selfinit1<<<(NN * 32 + 255) / 256, 256, 0, stream>>>(h1_part, dinv, h1_pre, out1);
    k_scatter1<<<(EE * 32 + 255) / 256, 256, 0, stream>>>(src, dst, dinv, h1_pre, out1);
    k_bias_relu1<<<(NN * 32 + 255) / 256, 256, 0, stream>>>(out1, b1);

    k_gemm2<<<(NN + 15) / 16, 256, 0, stream>>>(out1, W2, h2_pre);

    k_selfinit2<<<(NN * 16 + 255) / 256, 256, 0, stream>>>(h2_pre, dinv, out2);
    k_scatter2<<<(EE * 16 + 255) / 256, 256, 0, stream>>>(src, dst, dinv, h2_pre, out2);

    k_final2<<<(NN + 255) / 256, 256, 0, stream>>>(out2, b2, Wfc, s_arr, t_arr);
    k_pairs<<<(PP + 255) / 256, 256, 0, stream>>>(pair, s_arr, t_arr, bfc, out);
}

// Round 12
// 200.056 us; speedup vs baseline: 1.0432x; 1.0432x over previous
//
#include <hip/hip_runtime.h>
#include <math.h>

#define NN 10000
#define EE 320000
#define PP 200000
#define NTILES 320   // 10240/32 global 32-K tiles for W frag packing
#define KSPL 256     // K floats per split (1 KB per row per block)
#define NSPL 40      // 40*256 = 10240 >= 10000

typedef _Float16 h8v __attribute__((ext_vector_type(8)));  // 8 fp16 (A/B frag)
typedef __attribute__((ext_vector_type(4))) float f4v;     // 4 f32  (C/D frag)

#define GLOAD_LDS16(gsrc, ldst)                                                        \
    __builtin_amdgcn_global_load_lds((const __attribute__((address_space(1))) void*)(gsrc), \
                                     (__attribute__((address_space(3))) void*)(ldst), 16, 0, 0)

// fp32 -> fp16 RTNE bit pattern
__device__ __forceinline__ ushort f2h(float f) {
    union { _Float16 h; ushort u; } c;
    c.h = (_Float16)f;
    return c.u;
}

// ---------------- degree / norm ----------------
__global__ void k_deg_count(const int* __restrict__ dst, int* __restrict__ degi) {
    int e = blockIdx.x * blockDim.x + threadIdx.x;
    if (e < EE) atomicAdd(&degi[dst[e]], 1);
}

__global__ void k_dinv(const int* __restrict__ degi, float* __restrict__ dinv) {
    int n = blockIdx.x * blockDim.x + threadIdx.x;
    if (n < NN) dinv[n] = rsqrtf((float)(degi[n] + 1));  // +1 self loop
}

// ---------------- W1 -> fp16 in MFMA-fragment order ----------------
// w1f[((g*2+ct)*64 + lane)*8 + e] = fp16(W1[k][col]), k=g*32+(lane>>4)*8+e,
// col=ct*16+(lane&15); zero for k>=NN. 327,680 ushorts = 163,840 floats.
__global__ void k_wprep(const float* __restrict__ W1, ushort* __restrict__ wf) {
    int t = blockIdx.x * blockDim.x + threadIdx.x;
    if (t >= NTILES * 2 * 64 * 8) return;
    int e = t & 7, lane = (t >> 3) & 63, ct = (t >> 9) & 1, g = t >> 10;
    int col = ct * 16 + (lane & 15);
    int k = g * 32 + (lane >> 4) * 8 + e;
    wf[t] = (k < NN) ? f2h(W1[(long)k * 32 + col]) : (ushort)0;
}

// ---------------- GEMM1: h1_pre = x @ W1 (10000x10000 @ 10000x32), fp16 MFMA ----------------
// ONE-SHOT blocks, copy-benchmark structure: block = 64 rows x 256 K. Each wave
// stages its 16 rows via 16 global_load_lds, each 1 KB CONTIGUOUS from one row
// (perfect HBM granule); W = 8 subtile-frags in 64 VGPRs (loaded once, L2).
// Single vmcnt(0) drain -> 16 MFMA -> store partials -> block dies. NO loop,
// NO ring, NO barrier. LDS 66.5 KB -> 2 blocks/CU (8 waves); latency hidden by
// cross-block overlap (~32 KB in flight/CU). Grid (157, 40); no atomics.
__global__ __launch_bounds__(256) void k_gemm1(const float* __restrict__ x,
                                               const ushort* __restrict__ w1f,
                                               const float* __restrict__ zp,
                                               float* __restrict__ h1_part) {
    __shared__ __align__(16) float xs[4][16][260];   // 66,560 B -> 2 blocks/CU
    const int tid = threadIdx.x;
    const int lane = tid & 63;
    const int w = tid >> 6;            // wave 0..3
    const int fl = lane & 15;          // fragment row/col within 16
    const int khi = lane >> 4;         // fragment k-group 0..3
    const int ks = blockIdx.y;         // K-split 0..39
    const int wrow0 = blockIdx.x * 64 + w * 16;   // this wave's first row
    const int kbase = ks * KSPL;
    const long NN2 = (long)NN * NN;

    // ---- stage x: 16 insts, each ONE ROW x 1 KB contiguous (lane*16B) ----
#pragma unroll
    for (int j = 0; j < 16; ++j) {
        long flat = (long)(wrow0 + j) * NN + kbase + lane * 4;
        const float* src = (flat + 4 <= NN2) ? (x + flat) : zp;  // OOB row/tail -> 0
        GLOAD_LDS16(src, &xs[w][j][0]);
    }

    // ---- W frags -> 64 VGPRs (L2-resident w1f; compiler schedules) ----
    h8v wr[8][2];
#pragma unroll
    for (int kk = 0; kk < 8; ++kk)
#pragma unroll
        for (int ct = 0; ct < 2; ++ct)
            wr[kk][ct] = *(const h8v*)(w1f + ((long)((ks * 8 + kk) * 2 + ct) * 64 + lane) * 8);

    asm volatile("s_waitcnt vmcnt(0)" ::: "memory");   // single drain point
    __builtin_amdgcn_sched_barrier(0);

    // ---- compute: 8 subtiles of 32-K, 2 MFMA each ----
    f4v acc0 = (f4v){0.f, 0.f, 0.f, 0.f};
    f4v acc1 = (f4v){0.f, 0.f, 0.f, 0.f};
#pragma unroll
    for (int kk = 0; kk < 8; ++kk) {
        const float4* ap = (const float4*)&xs[w][fl][kk * 32 + khi * 8];
        float4 f0 = ap[0];
        float4 f1 = ap[1];
        union { h8v v; _Float16 h[8]; } a;
        a.h[0] = (_Float16)f0.x; a.h[1] = (_Float16)f0.y;
        a.h[2] = (_Float16)f0.z; a.h[3] = (_Float16)f0.w;
        a.h[4] = (_Float16)f1.x; a.h[5] = (_Float16)f1.y;
        a.h[6] = (_Float16)f1.z; a.h[7] = (_Float16)f1.w;
        acc0 = __builtin_amdgcn_mfma_f32_16x16x32_f16(a.v, wr[kk][0], acc0, 0, 0, 0);
        acc1 = __builtin_amdgcn_mfma_f32_16x16x32_f16(a.v, wr[kk][1], acc1, 0, 0, 0);
    }

    // ---- epilogue: plain stores to per-split partials (no atomics) ----
    const long pbase = (long)ks * NN * 32;
#pragma unroll
    for (int ct = 0; ct < 2; ++ct) {
        f4v a = ct ? acc1 : acc0;
        const int col = ct * 16 + fl;
#pragma unroll
        for (int r = 0; r < 4; ++r) {
            int g = wrow0 + khi * 4 + r;                 // C/D row = khi*4 + reg (m89)
            if (g < NN) h1_part[pbase + (long)g * 32 + col] = a[r];
        }
    }
}

// ---------------- reduce 40 partials + self-loop init (fused, float4) ----------------
__global__ void k_selfinit1(const float4* __restrict__ h1_part4, const float* __restrict__ dinv,
                            float4* __restrict__ h1_pre4, float4* __restrict__ out14) {
    int t = blockIdx.x * blockDim.x + threadIdx.x;
    if (t >= NN * 8) return;
    float4 s = make_float4(0.f, 0.f, 0.f, 0.f);
#pragma unroll
    for (int ks = 0; ks < NSPL; ++ks) {
        float4 v = h1_part4[(long)ks * NN * 8 + t];
        s.x += v.x; s.y += v.y; s.z += v.z; s.w += v.w;
    }
    int n = t >> 3;
    float d2 = dinv[n] * dinv[n];
    h1_pre4[t] = s;
    out14[t] = make_float4(s.x * d2, s.y * d2, s.z * d2, s.w * d2);
}

__global__ void k_scatter1(const int* __restrict__ src, const int* __restrict__ dst,
                           const float* __restrict__ dinv, const float* __restrict__ h1_pre,
                           float* __restrict__ out1) {
    int t = blockIdx.x * blockDim.x + threadIdx.x;
    if (t >= EE * 32) return;
    int e = t >> 5, c = t & 31;
    int s = src[e], d = dst[e];
    float nrm = dinv[s] * dinv[d];
    atomicAdd(&out1[d * 32 + c], h1_pre[s * 32 + c] * nrm);
}

__global__ void k_bias_relu1(float* __restrict__ out1, const float* __restrict__ b1) {
    int t = blockIdx.x * blockDim.x + threadIdx.x;
    if (t < NN * 32) out1[t] = fmaxf(out1[t] + b1[t & 31], 0.f);
}

// ---------------- GEMM2: h2_pre = out1 @ W2  (10000x32 @ 32x16), fp32 ----------------
__global__ __launch_bounds__(256) void k_gemm2(const float* __restrict__ out1,
                                               const float* __restrict__ W2,
                                               float* __restrict__ h2_pre) {
    __shared__ float w2s[512];
    int tid = threadIdx.x;
    w2s[tid] = W2[tid & 511];
    if (tid < 256) w2s[256 + tid] = W2[256 + tid];
    __syncthreads();
    int c = tid & 15, yloc = tid >> 4;
    int n = blockIdx.x * 16 + yloc;
    if (n < NN) {
        float a = 0.f;
#pragma unroll
        for (int k = 0; k < 32; ++k) a += out1[n * 32 + k] * w2s[k * 16 + c];
        h2_pre[n * 16 + c] = a;
    }
}

// ---------------- aggregation layer 2 (16 feats) ----------------
__global__ void k_selfinit2(const float* __restrict__ h2_pre, const float* __restrict__ dinv,
                            float* __restrict__ out2) {
    int t = blockIdx.x * blockDim.x + threadIdx.x;
    if (t < NN * 16) {
        int n = t >> 4;
        float di = dinv[n];
        out2[t] = di * di * h2_pre[t];
    }
}

__global__ void k_scatter2(const int* __restrict__ src, const int* __restrict__ dst,
                           const float* __restrict__ dinv, const float* __restrict__ h2_pre,
                           float* __restrict__ out2) {
    int t = blockIdx.x * blockDim.x + threadIdx.x;
    if (t >= EE * 16) return;
    int e = t >> 4, c = t & 15;
    int s = src[e], d = dst[e];
    float nrm = dinv[s] * dinv[d];
    atomicAdd(&out2[d * 16 + c], h2_pre[s * 16 + c] * nrm);
}

// ---------------- final: per-node partial dots with Wfc ----------------
__global__ void k_final2(const float* __restrict__ out2, const float* __restrict__ b2,
                         const float* __restrict__ Wfc, float* __restrict__ s_arr,
                         float* __restrict__ t_arr) {
    int n = blockIdx.x * blockDim.x + threadIdx.x;
    if (n >= NN) return;
    float s = 0.f, t = 0.f;
#pragma unroll
    for (int c = 0; c < 16; ++c) {
        float v = out2[n * 16 + c] + b2[c];
        s += v * Wfc[c];
        t += v * Wfc[16 + c];
    }
    s_arr[n] = s;
    t_arr[n] = t;
}

// ---------------- pair scoring ----------------
__global__ void k_pairs(const int* __restrict__ pair, const float* __restrict__ s_arr,
                        const float* __restrict__ t_arr, const float* __restrict__ bfc,
                        float* __restrict__ out) {
    int p = blockIdx.x * blockDim.x + threadIdx.x;
    if (p >= PP) return;
    const int2 ab = ((const int2*)pair)[p];
    float z = s_arr[ab.x] + t_arr[ab.y] + bfc[0];
    out[p] = 1.f / (1.f + expf(-z));
}

extern "C" void kernel_launch(void* const* d_in, const int* in_sizes, int n_in,
                              void* d_out, int out_size, void* d_ws, size_t ws_size,
                              hipStream_t stream) {
    const float* x    = (const float*)d_in[0];
    const int*   edge = (const int*)d_in[1];   // [2][E]
    const int*   pair = (const int*)d_in[2];   // [P][2]
    const float* W1   = (const float*)d_in[3];
    const float* b1   = (const float*)d_in[4];
    const float* W2   = (const float*)d_in[5];
    const float* b2   = (const float*)d_in[6];
    const float* Wfc  = (const float*)d_in[7];
    const float* bfc  = (const float*)d_in[8];
    float* out = (float*)d_out;
    float* ws  = (float*)d_ws;

    const int* src = edge;
    const int* dst = edge + EE;

    // workspace layout (floats)
    int*    degi    = (int*)ws;            // N
    float*  dinv    = ws + NN;             // N
    float*  h1_pre  = ws + 2 * NN;         // 32N
    float*  out1    = ws + 34 * NN;        // 32N
    float*  h2_pre  = ws + 66 * NN;        // 16N
    float*  out2    = ws + 82 * NN;        // 16N
    float*  s_arr   = ws + 98 * NN;        // N
    float*  t_arr   = ws + 99 * NN;        // N
    float*  zp      = ws + 100 * NN;       // 256 floats zero page
    ushort* w1f     = (ushort*)(ws + 100 * NN + 256);   // 327,680 ushorts = 163,840 floats
    float*  h1_part = ws + 100 * NN + 256 + 163840;     // 40 * 32N floats = 51.2 MB

    hipMemsetAsync(degi, 0, NN * sizeof(int), stream);
    hipMemsetAsync(zp, 0, 1024, stream);

    k_deg_count<<<(EE + 255) / 256, 256, 0, stream>>>(dst, degi);
    k_dinv<<<(NN + 255) / 256, 256, 0, stream>>>(degi, dinv);
    k_wprep<<<(NTILES * 2 * 64 * 8 + 255) / 256, 256, 0, stream>>>(W1, w1f);

    k_gemm1<<<dim3(157, NSPL), 256, 0, stream>>>(x, w1f, zp, h1_part);

    k_selfinit1<<<(NN * 8 + 255) / 256, 256, 0, stream>>>(
        (const float4*)h1_part, dinv, (float4*)h1_pre, (float4*)out1);
    k_scatter1<<<(EE * 32 + 255) / 256, 256, 0, stream>>>(src, dst, dinv, h1_pre, out1);
    k_bias_relu1<<<(NN * 32 + 255) / 256, 256, 0, stream>>>(out1, b1);

    k_gemm2<<<(NN + 15) / 16, 256, 0, stream>>>(out1, W2, h2_pre);

    k_selfinit2<<<(NN * 16 + 255) / 256, 256, 0, stream>>>(h2_pre, dinv, out2);
    k_scatter2<<<(EE * 16 + 255) / 256, 256, 0, stream>>>(src, dst, dinv, h2_pre, out2);

    k_final2<<<(NN + 255) / 256, 256, 0, stream>>>(out2, b2, Wfc, s_arr, t_arr);
    k_pairs<<<(PP + 255) / 256, 256, 0, stream>>>(pair, s_arr, t_arr, bfc, out);
}